// Round 3
// baseline (1537.616 us; speedup 1.0000x reference)
//
#include <hip/hip_runtime.h>

// NeuralConvNetwork (Duvenaud fingerprint GNN), MI355X.
// Round 11: layer_last -> persistent producer/consumer kernel (layer_lastPC).
//   R8/R9/R10 were all ~neutral: the invariant serial chain per chunk
//   (idx load -> row gather -> reduce -> GEMM) is the stall; in-order vmcnt
//   makes single-wave prefetch impossible (B-load use drains gathers).
//   Fix: wave specialization. Waves 0-3 consume (GEMM, vmcnt has only B),
//   waves 4-7 produce (gather chunk c+2 to regs, reduce chunk c+1 to LDS;
//   vmcnt has only gathers -> 1-iteration in-flight window, latency hidden).
//   500 persistent blocks x 25 chunks, degree-pure; double-buffered Hs.
// Layers 0/1 kept as R9 (2-chunk layer01).

#define XS 100   // bf16 elems per intermediate activation row (exact)

typedef __attribute__((ext_vector_type(8))) short short8;
typedef __attribute__((ext_vector_type(4))) float float4v;

__device__ __forceinline__ float bf2f(unsigned u) { return __uint_as_float(u << 16); }
__device__ __forceinline__ unsigned short f2bf(float f) {
    unsigned b = __float_as_uint(f);
    return (unsigned short)((b + 0x7FFFu + ((b >> 16) & 1u)) >> 16);  // RNE
}
__device__ __forceinline__ unsigned pack2(float a, float b) {
    return (unsigned)f2bf(a) | ((unsigned)f2bf(b) << 16);
}

// block id -> (deg, seg, pair, has1) for the 2-chunk layer01 grid (6251 blocks).
__device__ __forceinline__ void pairseg(int b, int& deg, int& seg, int& pair, bool& has1) {
    if (b < 1250)      { deg = 1; seg = 0;      pair = b;        has1 = true; }
    else if (b < 3438) { deg = 2; seg = 100000; pair = b - 1250; has1 = (pair != 2187); }
    else if (b < 5313) { deg = 3; seg = 275000; pair = b - 3438; has1 = true; }
    else               { deg = 4; seg = 425000; pair = b - 5313; has1 = (pair != 937); }
}

// ---- weight prep: Wt[dg][n][k]; k<F_IN -> Ws[k][n], SELF_PAD<=k<SELF_PAD+F_IN
//      -> Wd[dg][k-SELF_PAD][n], 2*SELF_PAD<=k<2*SELF_PAD+6 -> Wd bond rows.
__global__ void prep_weights(const float* __restrict__ Ws, const float* __restrict__ bs,
                             const float* __restrict__ Wd, const float* __restrict__ bd,
                             int F_IN, int F_OUT, int F_OUT_PAD, int KP, int SELF_PAD,
                             unsigned short* __restrict__ Wt, float* __restrict__ bc)
{
    int id = blockIdx.x * 256 + threadIdx.x;
    int total = 4 * F_OUT_PAD * KP;
    if (id >= total) return;
    int k  = id % KP;
    int nq = (id / KP) % F_OUT_PAD;
    int dg = id / (KP * F_OUT_PAD);
    float v = 0.f;
    if (nq < F_OUT) {
        if (k < F_IN)                                   v = Ws[(size_t)k * F_OUT + nq];
        else if (k >= SELF_PAD && k < SELF_PAD + F_IN)  v = Wd[((size_t)dg * (F_IN + 6) + (k - SELF_PAD)) * F_OUT + nq];
        else if (k >= 2 * SELF_PAD && k < 2 * SELF_PAD + 6)
            v = Wd[((size_t)dg * (F_IN + 6) + F_IN + (k - 2 * SELF_PAD)) * F_OUT + nq];
    }
    Wt[id] = f2bf(v);
    if (k == 0)
        bc[dg * F_OUT_PAD + nq] = (nq < F_OUT) ? (bs[nq] + bd[(size_t)dg * F_OUT + nq]) : 0.f;
}

// ======================= gathers, 256-thread variant (layer01) ===============
template<int DEG, int SP>
__device__ __forceinline__ void g256_bf16(
    unsigned short* Hs, const unsigned short* __restrict__ x,
    const float* __restrict__ bondf,
    const int* __restrict__ an, const int* __restrict__ bn,
    int seg, int B40, int tid)
{
    const int ch  = tid & 31;
    const int rr  = tid >> 5;                       // 0..7
    if (ch < 25) {
        int ai[5][DEG];
        #pragma unroll
        for (int p = 0; p < 5; ++p) {
            const int ri = B40 + rr + 8 * p;
            #pragma unroll
            for (int d = 0; d < DEG; ++d) ai[p][d] = an[(size_t)ri * DEG + d];
        }
        uint2 sv[5], nv[5][DEG];
        #pragma unroll
        for (int p = 0; p < 5; ++p) {
            const int atom = seg + B40 + rr + 8 * p;
            sv[p] = *(const uint2*)(x + (size_t)atom * XS + ch * 4);
            #pragma unroll
            for (int d = 0; d < DEG; ++d)
                nv[p][d] = *(const uint2*)(x + (size_t)ai[p][d] * XS + ch * 4);
        }
        #pragma unroll
        for (int p = 0; p < 5; ++p) {
            unsigned short* hrow = Hs + (rr + 8 * p) * SP;
            *(uint2*)(hrow + ch * 4) = sv[p];       // self: bit copy
            float s0 = 0.f, s1 = 0.f, s2 = 0.f, s3 = 0.f;
            #pragma unroll
            for (int d = 0; d < DEG; ++d) {
                s0 += bf2f(nv[p][d].x & 0xFFFFu); s1 += bf2f(nv[p][d].x >> 16);
                s2 += bf2f(nv[p][d].y & 0xFFFFu); s3 += bf2f(nv[p][d].y >> 16);
            }
            uint2 o; o.x = pack2(s0, s1); o.y = pack2(s2, s3);
            *(uint2*)(hrow + 104 + ch * 4) = o;
        }
    }
    if (tid < 40) {                                 // bond: one row per thread
        const int ri = B40 + tid;
        int bi[DEG];
        #pragma unroll
        for (int d = 0; d < DEG; ++d) bi[d] = bn[(size_t)ri * DEG + d];
        float2 v0[DEG], v1[DEG], v2[DEG];
        #pragma unroll
        for (int d = 0; d < DEG; ++d) {
            const float* bp = bondf + (size_t)bi[d] * 6;
            v0[d] = *(const float2*)bp;
            v1[d] = *(const float2*)(bp + 2);
            v2[d] = *(const float2*)(bp + 4);
        }
        float s0 = 0.f, s1 = 0.f, s2 = 0.f, s3 = 0.f, s4 = 0.f, s5 = 0.f;
        #pragma unroll
        for (int d = 0; d < DEG; ++d) {
            s0 += v0[d].x; s1 += v0[d].y; s2 += v1[d].x;
            s3 += v1[d].y; s4 += v2[d].x; s5 += v2[d].y;
        }
        unsigned short* hrow = Hs + tid * SP;
        uint4 w; w.x = pack2(s0, s1); w.y = pack2(s2, s3); w.z = pack2(s4, s5); w.w = 0;
        *(uint4*)(hrow + 208) = w;
        *(uint4*)(hrow + 216) = make_uint4(0, 0, 0, 0);
    }
    for (int i = tid; i < 80; i += 256) {
        unsigned short* p = Hs + (i >> 1) * SP + ((i & 1) ? 204 : 100);
        *(uint2*)p = make_uint2(0, 0);
    }
    for (int i = tid; i < 8 * 28; i += 256)
        *(uint4*)(Hs + (40 + i / 28) * SP + (i % 28) * 8) = make_uint4(0, 0, 0, 0);
}

template<int DEG, int SP>
__device__ __forceinline__ void g256_f32(
    unsigned short* Hs, const float* __restrict__ x,
    const float* __restrict__ bondf,
    const int* __restrict__ an, const int* __restrict__ bn,
    int seg, int B40, int tid)
{
    const int ch  = tid & 31;
    const int rr  = tid >> 5;
    if (ch < 31) {
        int ai[5][DEG];
        #pragma unroll
        for (int p = 0; p < 5; ++p) {
            const int ri = B40 + rr + 8 * p;
            #pragma unroll
            for (int d = 0; d < DEG; ++d) ai[p][d] = an[(size_t)ri * DEG + d];
        }
        float2 sv[5], nv[5][DEG];
        #pragma unroll
        for (int p = 0; p < 5; ++p) {
            const int atom = seg + B40 + rr + 8 * p;
            sv[p] = *(const float2*)(x + (size_t)atom * 62 + ch * 2);
            #pragma unroll
            for (int d = 0; d < DEG; ++d)
                nv[p][d] = *(const float2*)(x + (size_t)ai[p][d] * 62 + ch * 2);
        }
        #pragma unroll
        for (int p = 0; p < 5; ++p) {
            unsigned short* hrow = Hs + (rr + 8 * p) * SP;
            *(unsigned*)(hrow + ch * 2) = pack2(sv[p].x, sv[p].y);
            float s0 = 0.f, s1 = 0.f;
            #pragma unroll
            for (int d = 0; d < DEG; ++d) { s0 += nv[p][d].x; s1 += nv[p][d].y; }
            *(unsigned*)(hrow + 64 + ch * 2) = pack2(s0, s1);
        }
    }
    if (tid < 40) {
        const int ri = B40 + tid;
        int bi[DEG];
        #pragma unroll
        for (int d = 0; d < DEG; ++d) bi[d] = bn[(size_t)ri * DEG + d];
        float2 v0[DEG], v1[DEG], v2[DEG];
        #pragma unroll
        for (int d = 0; d < DEG; ++d) {
            const float* bp = bondf + (size_t)bi[d] * 6;
            v0[d] = *(const float2*)bp;
            v1[d] = *(const float2*)(bp + 2);
            v2[d] = *(const float2*)(bp + 4);
        }
        float s0 = 0.f, s1 = 0.f, s2 = 0.f, s3 = 0.f, s4 = 0.f, s5 = 0.f;
        #pragma unroll
        for (int d = 0; d < DEG; ++d) {
            s0 += v0[d].x; s1 += v0[d].y; s2 += v1[d].x;
            s3 += v1[d].y; s4 += v2[d].x; s5 += v2[d].y;
        }
        unsigned short* hrow = Hs + tid * SP;
        uint4 w; w.x = pack2(s0, s1); w.y = pack2(s2, s3); w.z = pack2(s4, s5); w.w = 0;
        *(uint4*)(hrow + 128) = w;
        *(uint4*)(hrow + 136) = make_uint4(0, 0, 0, 0);
        *(uint4*)(hrow + 144) = make_uint4(0, 0, 0, 0);
        *(uint4*)(hrow + 152) = make_uint4(0, 0, 0, 0);
    }
    for (int i = tid; i < 80; i += 256)
        *(unsigned*)(Hs + (i >> 1) * SP + ((i & 1) ? 126 : 62)) = 0;
    for (int i = tid; i < 8 * 20; i += 256)
        *(uint4*)(Hs + (40 + i / 20) * SP + (i % 20) * 8) = make_uint4(0, 0, 0, 0);
}

// ======================= layers 0/1: 2-chunk fused kernel (R9, proven) =======
template<int F_IN, int SELF_PAD, bool BF16IN>
__global__ __launch_bounds__(512, 4) void layer01(
    const void* __restrict__ xin,
    const float* __restrict__ bondf,
    const int* __restrict__ an1, const int* __restrict__ bn1,
    const int* __restrict__ an2, const int* __restrict__ bn2,
    const int* __restrict__ an3, const int* __restrict__ bn3,
    const int* __restrict__ an4, const int* __restrict__ bn4,
    const unsigned short* __restrict__ Wt,  // [4][112][KP] bf16
    const float* __restrict__ bcomb,        // [4][112] fp32
    unsigned short* __restrict__ xout)      // [500000, XS] bf16
{
    constexpr int F_OUT = 100;
    constexpr int F_OUT_PAD = 112;
    constexpr int KP = (2 * SELF_PAD + 6 + 31) & ~31;   // 160 / 224
    constexpr int SP = KP + 8;

    __shared__ __align__(16) unsigned short Hs[96 * SP];
    __shared__ float ssqs[7][96];
    __shared__ __align__(16) float rn96[96];

    const int b = blockIdx.x;
    int deg, seg, pair; bool has1;
    pairseg(b, deg, seg, pair, has1);

    const int half = threadIdx.x >> 8;
    const int t    = threadIdx.x & 255;
    const int B40  = pair * 80 + half * 40;
    unsigned short* HsC = Hs + half * 48 * SP;

    if (half == 1 && !has1) {
        for (int i = t; i < 48 * SP / 8; i += 256)
            ((uint4*)HsC)[i] = make_uint4(0, 0, 0, 0);
    } else {
        if constexpr (BF16IN) {
            const unsigned short* x = (const unsigned short*)xin;
            switch (deg) {
                case 1: g256_bf16<1, SP>(HsC, x, bondf, an1, bn1, seg, B40, t); break;
                case 2: g256_bf16<2, SP>(HsC, x, bondf, an2, bn2, seg, B40, t); break;
                case 3: g256_bf16<3, SP>(HsC, x, bondf, an3, bn3, seg, B40, t); break;
                default: g256_bf16<4, SP>(HsC, x, bondf, an4, bn4, seg, B40, t); break;
            }
        } else {
            const float* x = (const float*)xin;
            switch (deg) {
                case 1: g256_f32<1, SP>(HsC, x, bondf, an1, bn1, seg, B40, t); break;
                case 2: g256_f32<2, SP>(HsC, x, bondf, an2, bn2, seg, B40, t); break;
                case 3: g256_f32<3, SP>(HsC, x, bondf, an3, bn3, seg, B40, t); break;
                default: g256_f32<4, SP>(HsC, x, bondf, an4, bn4, seg, B40, t); break;
            }
        }
    }
    __syncthreads();

    const int lane = threadIdx.x & 63;
    const int wv   = threadIdx.x >> 6;
    const int n16  = lane & 15;
    const int quad = lane >> 4;

    float4v acc[6];
    #pragma unroll
    for (int mt = 0; mt < 6; ++mt) acc[mt] = (float4v){0.f, 0.f, 0.f, 0.f};

    if (wv < 7) {
        const unsigned short* Wr =
            Wt + ((size_t)(deg - 1) * F_OUT_PAD + wv * 16 + n16) * KP;
        #pragma unroll
        for (int kk = 0; kk < KP; kk += 32) {
            short8 bb = *(const short8*)(Wr + kk + quad * 8);
            short8 a[6];
            #pragma unroll
            for (int mt = 0; mt < 6; ++mt)
                a[mt] = *(const short8*)&Hs[(mt * 16 + n16) * SP + kk + quad * 8];
            #pragma unroll
            for (int mt = 0; mt < 6; ++mt)
                acc[mt] = __builtin_amdgcn_mfma_f32_16x16x32_bf16(a[mt], bb, acc[mt], 0, 0, 0);
        }
    }

    float ssq[6][4];
    #pragma unroll
    for (int mt = 0; mt < 6; ++mt)
        #pragma unroll
        for (int r = 0; r < 4; ++r) ssq[mt][r] = 0.f;

    if (wv < 7) {
        const float bj = bcomb[(deg - 1) * F_OUT_PAD + wv * 16 + n16];
        #pragma unroll
        for (int mt = 0; mt < 6; ++mt)
            #pragma unroll
            for (int r = 0; r < 4; ++r) {
                float v = acc[mt][r] + bj;
                acc[mt][r] = v;
                ssq[mt][r] += v * v;
            }
        #pragma unroll
        for (int off = 1; off <= 8; off <<= 1)
            #pragma unroll
            for (int mt = 0; mt < 6; ++mt)
                #pragma unroll
                for (int r = 0; r < 4; ++r)
                    ssq[mt][r] += __shfl_xor(ssq[mt][r], off);
        if (n16 == 0)
            #pragma unroll
            for (int mt = 0; mt < 6; ++mt)
                #pragma unroll
                for (int r = 0; r < 4; ++r)
                    ssqs[wv][mt * 16 + quad * 4 + r] = ssq[mt][r];
    }
    __syncthreads();

    if (threadIdx.x < 96) {
        float s = 0.f;
        #pragma unroll
        for (int w = 0; w < 7; ++w) s += ssqs[w][threadIdx.x];
        rn96[threadIdx.x] = 1.0f / fmaxf(sqrtf(s), 1e-12f);
    }
    __syncthreads();

    const int col = wv * 16 + n16;
    if (wv < 7 && col < F_OUT) {
        #pragma unroll
        for (int mt = 0; mt < 6; ++mt) {
            const int chunk = mt / 3;
            if (chunk == 0 || has1) {
                float4 rv = *(const float4*)&rn96[mt * 16 + quad * 4];
                const float rn_[4] = {rv.x, rv.y, rv.z, rv.w};
                const int rowc0 = (mt % 3) * 16 + quad * 4;
                const int gbase = seg + pair * 80 + chunk * 40 + rowc0;
                #pragma unroll
                for (int r = 0; r < 4; ++r) {
                    if (rowc0 + r < 40) {
                        const float v = fmaxf(acc[mt][r] * rn_[r], 0.f);
                        xout[(size_t)(gbase + r) * XS + col] = f2bf(v);
                    }
                }
            }
        }
    }
}

// ======================= layer 2: producer/consumer persistent (R11) =========
// 500 blocks x 512 threads; block b owns 25 degree-pure chunks.
// Waves 0-3: consumers (GEMM 48x512 from Hs[pb] + Wt; epilogue; molout).
// Waves 4-7: producers (reduce chunk c+1 regs -> Hs[pb^1]; fetch chunk c+2).
// Producer vmcnt queue has NO B-loads -> gathers get a full iteration in
// flight. Consumer vmcnt has only B-loads -> normal GEMM pipelining.
template<int DEG>
__device__ __forceinline__ void lastPC(
    unsigned short* Hs, float (*ssqs)[48], float* rn48,
    const unsigned short* __restrict__ x, const float* __restrict__ bondf,
    const int* __restrict__ an, const int* __restrict__ bn,
    const unsigned short* __restrict__ Wt, const float* __restrict__ bcomb,
    float* __restrict__ molout, int c0, int seg)
{
    constexpr int KP = 224, SP = 232;
    constexpr int HSZ = 48 * SP;
    const int tid = threadIdx.x;

    // zero both buffers once; pad regions persist, live regions rewritten.
    for (int i = tid; i < 2 * HSZ / 8; i += 512)
        ((uint4*)Hs)[i] = make_uint4(0, 0, 0, 0);

    const bool cons = tid < 256;
    const int lane = tid & 63, wv = tid >> 6, n16 = lane & 15, quad = lane >> 4;
    const int pt = tid - 256;   // producer thread id 0..255 (garbage for cons)

    // producer register state (live only in producer threads' branches)
    uint2  valS[5];        // self: pt<200, units uu = k*200+pt -> (s,ch)
    uint2  valN[4][DEG];   // nbr:  pt<250, units uu = k*250+pt -> (r,ch)
    float2 valB[DEG];      // bond: pt<120, unit (r,j) = (pt/3, pt%3)

    // fetch chunk cc: transient idx loads, then row loads held to next iter.
    auto fetch_chunk = [&](int cc) {
        const int B40c = cc * 40 - seg;
        const int R0c  = cc * 40;
        if (pt < 250) {
            int ix[4][DEG];
            #pragma unroll
            for (int k = 0; k < 4; ++k) {
                const int r = (k * 250 + pt) / 25;
                #pragma unroll
                for (int d = 0; d < DEG; ++d)
                    ix[k][d] = an[(size_t)(B40c + r) * DEG + d];
            }
            #pragma unroll
            for (int k = 0; k < 4; ++k) {
                const int ch = (k * 250 + pt) % 25;
                #pragma unroll
                for (int d = 0; d < DEG; ++d)
                    valN[k][d] = *(const uint2*)(x + (size_t)ix[k][d] * XS + ch * 4);
            }
        }
        if (pt < 200) {
            #pragma unroll
            for (int k = 0; k < 5; ++k) {
                const int uu = k * 200 + pt, s = uu / 25, ch = uu % 25;
                valS[k] = *(const uint2*)(x + (size_t)(R0c + s) * XS + ch * 4);
            }
        }
        if (pt < 120) {
            const int r = pt / 3, j = pt - 3 * r;
            int ib[DEG];
            #pragma unroll
            for (int d = 0; d < DEG; ++d) ib[d] = bn[(size_t)(B40c + r) * DEG + d];
            #pragma unroll
            for (int d = 0; d < DEG; ++d)
                valB[d] = *(const float2*)(bondf + (size_t)ib[d] * 6 + j * 2);
        }
    };
    auto reduce_write = [&](unsigned short* Hw) {
        if (pt < 250) {
            #pragma unroll
            for (int k = 0; k < 4; ++k) {
                const int uu = k * 250 + pt, r = uu / 25, ch = uu % 25;
                float s0 = 0.f, s1 = 0.f, s2 = 0.f, s3 = 0.f;
                #pragma unroll
                for (int d = 0; d < DEG; ++d) {
                    s0 += bf2f(valN[k][d].x & 0xFFFFu); s1 += bf2f(valN[k][d].x >> 16);
                    s2 += bf2f(valN[k][d].y & 0xFFFFu); s3 += bf2f(valN[k][d].y >> 16);
                }
                uint2 o; o.x = pack2(s0, s1); o.y = pack2(s2, s3);
                *(uint2*)(Hw + r * SP + 104 + ch * 4) = o;
            }
        }
        if (pt < 200) {
            #pragma unroll
            for (int k = 0; k < 5; ++k) {
                const int uu = k * 200 + pt, s = uu / 25, ch = uu % 25;
                *(uint2*)(Hw + s * SP + ch * 4) = valS[k];
            }
        }
        if (pt < 120) {
            const int r = pt / 3, j = pt - 3 * r;
            float sx = 0.f, sy = 0.f;
            #pragma unroll
            for (int d = 0; d < DEG; ++d) { sx += valB[d].x; sy += valB[d].y; }
            *(unsigned*)(Hw + r * SP + 208 + j * 2) = pack2(sx, sy);
        }
    };

    // consumer constants
    const unsigned short* Wb = Wt + (size_t)(DEG - 1) * 512 * KP;
    float bj[8];
    if (cons) {
        #pragma unroll
        for (int j = 0; j < 8; ++j)
            bj[j] = bcomb[(DEG - 1) * 512 + (wv + 4 * j) * 16 + n16];
    }

    // prologue: fill buffer 0 with chunk c0; prefetch chunk c0+1 to regs.
    if (!cons) {
        fetch_chunk(c0);
        reduce_write(Hs);          // waits rows(c0); one exposed latency
        fetch_chunk(c0 + 1);
    }
    __syncthreads();

    int pb = 0;
    for (int ci = 0; ci < 25; ++ci) {
        const int c = c0 + ci;
        const unsigned short* Hr = Hs + pb * HSZ;
        unsigned short* Hw = Hs + (pb ^ 1) * HSZ;

        float4v acc[8][3];
        if (cons) {
            #pragma unroll
            for (int j = 0; j < 8; ++j)
                #pragma unroll
                for (int mt = 0; mt < 3; ++mt)
                    acc[j][mt] = (float4v){0.f, 0.f, 0.f, 0.f};
            #pragma unroll
            for (int kk = 0; kk < KP; kk += 32) {
                short8 a[3];
                #pragma unroll
                for (int mt = 0; mt < 3; ++mt)
                    a[mt] = *(const short8*)&Hr[(mt * 16 + n16) * SP + kk + quad * 8];
                short8 bfr[8];
                #pragma unroll
                for (int j = 0; j < 8; ++j)
                    bfr[j] = *(const short8*)(Wb + (size_t)((wv + 4 * j) * 16 + n16) * KP + kk + quad * 8);
                #pragma unroll
                for (int j = 0; j < 8; ++j)
                    #pragma unroll
                    for (int mt = 0; mt < 3; ++mt)
                        acc[j][mt] = __builtin_amdgcn_mfma_f32_16x16x32_bf16(
                            a[mt], bfr[j], acc[j][mt], 0, 0, 0);
            }
            // bias + row sum-of-squares
            float ssq[3][4];
            #pragma unroll
            for (int mt = 0; mt < 3; ++mt)
                #pragma unroll
                for (int r = 0; r < 4; ++r) ssq[mt][r] = 0.f;
            #pragma unroll
            for (int j = 0; j < 8; ++j)
                #pragma unroll
                for (int mt = 0; mt < 3; ++mt)
                    #pragma unroll
                    for (int r = 0; r < 4; ++r) {
                        float v = acc[j][mt][r] + bj[j];
                        acc[j][mt][r] = v;
                        ssq[mt][r] += v * v;
                    }
            #pragma unroll
            for (int off = 1; off <= 8; off <<= 1)
                #pragma unroll
                for (int mt = 0; mt < 3; ++mt)
                    #pragma unroll
                    for (int r = 0; r < 4; ++r)
                        ssq[mt][r] += __shfl_xor(ssq[mt][r], off);
            if (n16 == 0)
                #pragma unroll
                for (int mt = 0; mt < 3; ++mt)
                    #pragma unroll
                    for (int r = 0; r < 4; ++r)
                        ssqs[wv][mt * 16 + quad * 4 + r] = ssq[mt][r];
        } else {
            if (ci + 1 < 25) reduce_write(Hw);     // rows fetched last iter
            if (ci + 2 < 25) fetch_chunk(c + 2);   // full-iteration window
        }
        __syncthreads();

        if (tid < 48) {
            float s = ssqs[0][tid] + ssqs[1][tid] + ssqs[2][tid] + ssqs[3][tid];
            rn48[tid] = 1.0f / fmaxf(sqrtf(s), 1e-12f);
        }
        __syncthreads();

        if (cons) {
            float rn_[3][4];
            #pragma unroll
            for (int mt = 0; mt < 3; ++mt) {
                float4 v = *(const float4*)&rn48[mt * 16 + quad * 4];
                rn_[mt][0] = v.x; rn_[mt][1] = v.y; rn_[mt][2] = v.z; rn_[mt][3] = v.w;
            }
            #pragma unroll
            for (int j = 0; j < 8; ++j) {
                float m0 = 0.f, m1 = 0.f;
                #pragma unroll
                for (int mt = 0; mt < 3; ++mt)
                    #pragma unroll
                    for (int r = 0; r < 4; ++r) {
                        const int row = mt * 16 + quad * 4 + r;
                        if (row < 40) {
                            const float v = fmaxf(acc[j][mt][r] * rn_[mt][r], 0.f);
                            if (row < 20) m0 += v; else m1 += v;
                        }
                    }
                m0 += __shfl_xor(m0, 16); m0 += __shfl_xor(m0, 32);
                m1 += __shfl_xor(m1, 16); m1 += __shfl_xor(m1, 32);
                if (quad == 0) {
                    const int col = (wv + 4 * j) * 16 + n16;
                    molout[(size_t)(2 * c)     * 512 + col] = m0;
                    molout[(size_t)(2 * c + 1) * 512 + col] = m1;
                }
            }
        }
        pb ^= 1;
    }
}

__global__ __launch_bounds__(512, 2) void layer_lastPC(
    const unsigned short* __restrict__ x,
    const float* __restrict__ bondf,
    const int* __restrict__ an1, const int* __restrict__ bn1,
    const int* __restrict__ an2, const int* __restrict__ bn2,
    const int* __restrict__ an3, const int* __restrict__ bn3,
    const int* __restrict__ an4, const int* __restrict__ bn4,
    const unsigned short* __restrict__ Wt,  // [4][512][224] bf16
    const float* __restrict__ bcomb,        // [4][512] fp32
    float* __restrict__ molout)             // [25000, 512] fp32
{
    __shared__ __align__(16) unsigned short Hs[2 * 48 * 232];
    __shared__ float ssqs[4][48];
    __shared__ __align__(16) float rn48[48];

    const int b = blockIdx.x;
    // chunks/deg = {2500,4375,3750,1875} = 25*{100,175,150,75}; degree-pure.
    if (b < 100)
        lastPC<1>(Hs, ssqs, rn48, x, bondf, an1, bn1, Wt, bcomb, molout,
                  b * 25, 0);
    else if (b < 275)
        lastPC<2>(Hs, ssqs, rn48, x, bondf, an2, bn2, Wt, bcomb, molout,
                  2500 + (b - 100) * 25, 100000);
    else if (b < 425)
        lastPC<3>(Hs, ssqs, rn48, x, bondf, an3, bn3, Wt, bcomb, molout,
                  6875 + (b - 275) * 25, 275000);
    else
        lastPC<4>(Hs, ssqs, rn48, x, bondf, an4, bn4, Wt, bcomb, molout,
                  10625 + (b - 425) * 25, 425000);
}

extern "C" void kernel_launch(void* const* d_in, const int* in_sizes, int n_in,
                              void* d_out, int out_size, void* d_ws, size_t ws_size,
                              hipStream_t stream) {
    const bool sig_order = (in_sizes[3] != 100000);

    const float* atomf = (const float*)d_in[0];   // [500000,62]
    const float* bondf = (const float*)d_in[1];   // [600000,6]
    const int *an1, *bn1, *an2, *bn2, *an3, *bn3, *an4, *bn4;
    const float *Ws0, *bs0, *Wd0, *bd0;
    const float *Ws1, *bs1, *Wd1, *bd1;
    const float *Ws2, *bs2, *Wd2, *bd2;

    if (!sig_order) {
        an1 = (const int*)d_in[2];  bn1 = (const int*)d_in[3];
        an2 = (const int*)d_in[4];  bn2 = (const int*)d_in[5];
        an3 = (const int*)d_in[6];  bn3 = (const int*)d_in[7];
        an4 = (const int*)d_in[8];  bn4 = (const int*)d_in[9];
        Ws0 = (const float*)d_in[11]; bs0 = (const float*)d_in[12];
        Wd0 = (const float*)d_in[13]; bd0 = (const float*)d_in[14];
        Ws1 = (const float*)d_in[15]; bs1 = (const float*)d_in[16];
        Wd1 = (const float*)d_in[17]; bd1 = (const float*)d_in[18];
        Ws2 = (const float*)d_in[19]; bs2 = (const float*)d_in[20];
        Wd2 = (const float*)d_in[21]; bd2 = (const float*)d_in[22];
    } else {
        an1 = (const int*)d_in[2];  an2 = (const int*)d_in[3];
        an3 = (const int*)d_in[4];  an4 = (const int*)d_in[5];
        bn1 = (const int*)d_in[6];  bn2 = (const int*)d_in[7];
        bn3 = (const int*)d_in[8];  bn4 = (const int*)d_in[9];
        Ws0 = (const float*)d_in[11]; bs0 = (const float*)d_in[12];
        Ws1 = (const float*)d_in[13]; bs1 = (const float*)d_in[14];
        Ws2 = (const float*)d_in[15]; bs2 = (const float*)d_in[16];
        Wd0 = (const float*)d_in[17]; bd0 = (const float*)d_in[18];
        Wd1 = (const float*)d_in[19]; bd1 = (const float*)d_in[20];
        Wd2 = (const float*)d_in[21]; bd2 = (const float*)d_in[22];
    }

    // workspace layout (201,273,344 B — proven footprint)
    char* w = (char*)d_ws;
    unsigned short* x1  = (unsigned short*)w;                        // 100,000,000 B
    unsigned short* x2  = (unsigned short*)(w + 100000000);          // 100,000,000 B
    unsigned short* Wt0 = (unsigned short*)(w + 200000000);          // 143,360
    float*          bc0 = (float*)(w + 200143360);                   // 1,792
    unsigned short* Wt1 = (unsigned short*)(w + 200145152);          // 200,704
    float*          bc1 = (float*)(w + 200345856);                   // 1,792
    unsigned short* Wt2 = (unsigned short*)(w + 200347648);          // 917,504
    float*          bc2 = (float*)(w + 201265152);                   // 8,192

    prep_weights<<<(4 * 112 * 160 + 255) / 256, 256, 0, stream>>>(
        Ws0, bs0, Wd0, bd0, 62, 100, 112, 160, 64, Wt0, bc0);
    prep_weights<<<(4 * 112 * 224 + 255) / 256, 256, 0, stream>>>(
        Ws1, bs1, Wd1, bd1, 100, 100, 112, 224, 104, Wt1, bc1);
    prep_weights<<<(4 * 512 * 224 + 255) / 256, 256, 0, stream>>>(
        Ws2, bs2, Wd2, bd2, 100, 512, 512, 224, 104, Wt2, bc2);

    layer01<62, 64, false><<<6251, 512, 0, stream>>>(
        atomf, bondf, an1, bn1, an2, bn2, an3, bn3, an4, bn4, Wt0, bc0, x1);
    layer01<100, 104, true><<<6251, 512, 0, stream>>>(
        x1, bondf, an1, bn1, an2, bn2, an3, bn3, an4, bn4, Wt1, bc1, x2);
    layer_lastPC<<<500, 512, 0, stream>>>(
        x2, bondf, an1, bn1, an2, bn2, an3, bn3, an4, bn4,
        Wt2, bc2, (float*)d_out);
}

// Round 4
// 768.486 us; speedup vs baseline: 2.0008x; 2.0008x over previous
//
#include <hip/hip_runtime.h>

// NeuralConvNetwork (Duvenaud fingerprint GNN), MI355X.
// Round 12: consolidation + scattered-byte reduction.
//   R11 post-mortem: producer/consumer spilled (FETCH 886MB, WRITE 295MB =
//   scratch traffic; cross-barrier reg state union-allocated with consumer).
//   Robust signal R8-R11: every healthy variant pins at ~1.1 TB/s HBM with
//   FETCH ~= logical scattered volume -> layers are scattered-traffic-bound.
//   This round: revert to proven best (R9 layer01 + R8 layer_last), and
//   halve layer-0's scattered bytes: prepass casts atomf fp32 -> bf16 rows
//   padded to 64 cols (into the x2 region, dead until layer 1); layer 0
//   gathers bf16 (g256_bf16_64, same KP=160 Hs layout as the old f32 path).

#define XS 100   // bf16 elems per intermediate activation row (exact)

typedef __attribute__((ext_vector_type(8))) short short8;
typedef __attribute__((ext_vector_type(4))) float float4v;

__device__ __forceinline__ float bf2f(unsigned u) { return __uint_as_float(u << 16); }
__device__ __forceinline__ unsigned short f2bf(float f) {
    unsigned b = __float_as_uint(f);
    return (unsigned short)((b + 0x7FFFu + ((b >> 16) & 1u)) >> 16);  // RNE
}
__device__ __forceinline__ unsigned pack2(float a, float b) {
    return (unsigned)f2bf(a) | ((unsigned)f2bf(b) << 16);
}
__device__ __forceinline__ void rowseg(int r, int& deg, int& seg) {
    if (r < 100000)      { deg = 1; seg = 0;      }
    else if (r < 275000) { deg = 2; seg = 100000; }
    else if (r < 425000) { deg = 3; seg = 275000; }
    else                 { deg = 4; seg = 425000; }
}

// block id -> (deg, seg, pair, has1) for the 2-chunk grids (6251 blocks).
__device__ __forceinline__ void pairseg(int b, int& deg, int& seg, int& pair, bool& has1) {
    if (b < 1250)      { deg = 1; seg = 0;      pair = b;        has1 = true; }
    else if (b < 3438) { deg = 2; seg = 100000; pair = b - 1250; has1 = (pair != 2187); }
    else if (b < 5313) { deg = 3; seg = 275000; pair = b - 3438; has1 = true; }
    else               { deg = 4; seg = 425000; pair = b - 5313; has1 = (pair != 937); }
}

// ---- weight prep: Wt[dg][n][k]; k<F_IN -> Ws[k][n], SELF_PAD<=k<SELF_PAD+F_IN
//      -> Wd[dg][k-SELF_PAD][n], 2*SELF_PAD<=k<2*SELF_PAD+6 -> Wd bond rows.
__global__ void prep_weights(const float* __restrict__ Ws, const float* __restrict__ bs,
                             const float* __restrict__ Wd, const float* __restrict__ bd,
                             int F_IN, int F_OUT, int F_OUT_PAD, int KP, int SELF_PAD,
                             unsigned short* __restrict__ Wt, float* __restrict__ bc)
{
    int id = blockIdx.x * 256 + threadIdx.x;
    int total = 4 * F_OUT_PAD * KP;
    if (id >= total) return;
    int k  = id % KP;
    int nq = (id / KP) % F_OUT_PAD;
    int dg = id / (KP * F_OUT_PAD);
    float v = 0.f;
    if (nq < F_OUT) {
        if (k < F_IN)                                   v = Ws[(size_t)k * F_OUT + nq];
        else if (k >= SELF_PAD && k < SELF_PAD + F_IN)  v = Wd[((size_t)dg * (F_IN + 6) + (k - SELF_PAD)) * F_OUT + nq];
        else if (k >= 2 * SELF_PAD && k < 2 * SELF_PAD + 6)
            v = Wd[((size_t)dg * (F_IN + 6) + F_IN + (k - 2 * SELF_PAD)) * F_OUT + nq];
    }
    Wt[id] = f2bf(v);
    if (k == 0)
        bc[dg * F_OUT_PAD + nq] = (nq < F_OUT) ? (bs[nq] + bd[(size_t)dg * F_OUT + nq]) : 0.f;
}

// ---- atomf fp32 [500000,62] -> bf16 [500000,64] (2 zero pad cols) ----------
__global__ void prep_atom64(const float* __restrict__ af, unsigned* __restrict__ xo)
{
    int id = blockIdx.x * 256 + threadIdx.x;
    if (id >= 500000 * 32) return;
    const int row = id >> 5, c = id & 31, col = 2 * c;
    float a = (col < 62)     ? af[(size_t)row * 62 + col]     : 0.f;
    float b = (col + 1 < 62) ? af[(size_t)row * 62 + col + 1] : 0.f;
    xo[(size_t)row * 32 + c] = pack2(a, b);
}

// ======================= gathers, 256-thread variants ========================
// tid is passed in so two 256-thread halves of a 512 block can run in parallel.

// 100-elem bf16 rows (layers 1/2 input). Hs: self[0,100) nsum[104,204) bond[208,214).
template<int DEG, int SP>
__device__ __forceinline__ void g256_bf16(
    unsigned short* Hs, const unsigned short* __restrict__ x,
    const float* __restrict__ bondf,
    const int* __restrict__ an, const int* __restrict__ bn,
    int seg, int B40, int tid)
{
    const int ch  = tid & 31;
    const int rr  = tid >> 5;                       // 0..7
    if (ch < 25) {
        int ai[5][DEG];
        #pragma unroll
        for (int p = 0; p < 5; ++p) {
            const int ri = B40 + rr + 8 * p;
            #pragma unroll
            for (int d = 0; d < DEG; ++d) ai[p][d] = an[(size_t)ri * DEG + d];
        }
        uint2 sv[5], nv[5][DEG];
        #pragma unroll
        for (int p = 0; p < 5; ++p) {
            const int atom = seg + B40 + rr + 8 * p;
            sv[p] = *(const uint2*)(x + (size_t)atom * XS + ch * 4);
            #pragma unroll
            for (int d = 0; d < DEG; ++d)
                nv[p][d] = *(const uint2*)(x + (size_t)ai[p][d] * XS + ch * 4);
        }
        #pragma unroll
        for (int p = 0; p < 5; ++p) {
            unsigned short* hrow = Hs + (rr + 8 * p) * SP;
            *(uint2*)(hrow + ch * 4) = sv[p];       // self: bit copy
            float s0 = 0.f, s1 = 0.f, s2 = 0.f, s3 = 0.f;
            #pragma unroll
            for (int d = 0; d < DEG; ++d) {
                s0 += bf2f(nv[p][d].x & 0xFFFFu); s1 += bf2f(nv[p][d].x >> 16);
                s2 += bf2f(nv[p][d].y & 0xFFFFu); s3 += bf2f(nv[p][d].y >> 16);
            }
            uint2 o; o.x = pack2(s0, s1); o.y = pack2(s2, s3);
            *(uint2*)(hrow + 104 + ch * 4) = o;
        }
    }
    if (tid < 40) {                                 // bond: one row per thread
        const int ri = B40 + tid;
        int bi[DEG];
        #pragma unroll
        for (int d = 0; d < DEG; ++d) bi[d] = bn[(size_t)ri * DEG + d];
        float2 v0[DEG], v1[DEG], v2[DEG];
        #pragma unroll
        for (int d = 0; d < DEG; ++d) {
            const float* bp = bondf + (size_t)bi[d] * 6;
            v0[d] = *(const float2*)bp;
            v1[d] = *(const float2*)(bp + 2);
            v2[d] = *(const float2*)(bp + 4);
        }
        float s0 = 0.f, s1 = 0.f, s2 = 0.f, s3 = 0.f, s4 = 0.f, s5 = 0.f;
        #pragma unroll
        for (int d = 0; d < DEG; ++d) {
            s0 += v0[d].x; s1 += v0[d].y; s2 += v1[d].x;
            s3 += v1[d].y; s4 += v2[d].x; s5 += v2[d].y;
        }
        unsigned short* hrow = Hs + tid * SP;
        uint4 w; w.x = pack2(s0, s1); w.y = pack2(s2, s3); w.z = pack2(s4, s5); w.w = 0;
        *(uint4*)(hrow + 208) = w;
        *(uint4*)(hrow + 216) = make_uint4(0, 0, 0, 0);
    }
    for (int i = tid; i < 80; i += 256) {
        unsigned short* p = Hs + (i >> 1) * SP + ((i & 1) ? 204 : 100);
        *(uint2*)p = make_uint2(0, 0);
    }
    for (int i = tid; i < 8 * 28; i += 256)
        *(uint4*)(Hs + (40 + i / 28) * SP + (i % 28) * 8) = make_uint4(0, 0, 0, 0);
}

// 64-elem bf16 rows (layer 0 input, padded atomf). KP=160 layout:
// self[0,64) nsum[64,128) bond[128,134); zeros to 160. Mirrors old f32 path.
template<int DEG, int SP>
__device__ __forceinline__ void g256_bf16_64(
    unsigned short* Hs, const unsigned short* __restrict__ x,
    const float* __restrict__ bondf,
    const int* __restrict__ an, const int* __restrict__ bn,
    int seg, int B40, int tid)
{
    const int ch  = tid & 31;
    const int rr  = tid >> 5;                       // 0..7
    if (ch < 16) {
        int ai[5][DEG];
        #pragma unroll
        for (int p = 0; p < 5; ++p) {
            const int ri = B40 + rr + 8 * p;
            #pragma unroll
            for (int d = 0; d < DEG; ++d) ai[p][d] = an[(size_t)ri * DEG + d];
        }
        uint2 sv[5], nv[5][DEG];
        #pragma unroll
        for (int p = 0; p < 5; ++p) {
            const int atom = seg + B40 + rr + 8 * p;
            sv[p] = *(const uint2*)(x + (size_t)atom * 64 + ch * 4);
            #pragma unroll
            for (int d = 0; d < DEG; ++d)
                nv[p][d] = *(const uint2*)(x + (size_t)ai[p][d] * 64 + ch * 4);
        }
        #pragma unroll
        for (int p = 0; p < 5; ++p) {
            unsigned short* hrow = Hs + (rr + 8 * p) * SP;
            *(uint2*)(hrow + ch * 4) = sv[p];       // self: bit copy
            float s0 = 0.f, s1 = 0.f, s2 = 0.f, s3 = 0.f;
            #pragma unroll
            for (int d = 0; d < DEG; ++d) {
                s0 += bf2f(nv[p][d].x & 0xFFFFu); s1 += bf2f(nv[p][d].x >> 16);
                s2 += bf2f(nv[p][d].y & 0xFFFFu); s3 += bf2f(nv[p][d].y >> 16);
            }
            uint2 o; o.x = pack2(s0, s1); o.y = pack2(s2, s3);
            *(uint2*)(hrow + 64 + ch * 4) = o;
        }
    }
    if (tid < 40) {                                 // bond: one row per thread
        const int ri = B40 + tid;
        int bi[DEG];
        #pragma unroll
        for (int d = 0; d < DEG; ++d) bi[d] = bn[(size_t)ri * DEG + d];
        float2 v0[DEG], v1[DEG], v2[DEG];
        #pragma unroll
        for (int d = 0; d < DEG; ++d) {
            const float* bp = bondf + (size_t)bi[d] * 6;
            v0[d] = *(const float2*)bp;
            v1[d] = *(const float2*)(bp + 2);
            v2[d] = *(const float2*)(bp + 4);
        }
        float s0 = 0.f, s1 = 0.f, s2 = 0.f, s3 = 0.f, s4 = 0.f, s5 = 0.f;
        #pragma unroll
        for (int d = 0; d < DEG; ++d) {
            s0 += v0[d].x; s1 += v0[d].y; s2 += v1[d].x;
            s3 += v1[d].y; s4 += v2[d].x; s5 += v2[d].y;
        }
        unsigned short* hrow = Hs + tid * SP;
        uint4 w; w.x = pack2(s0, s1); w.y = pack2(s2, s3); w.z = pack2(s4, s5); w.w = 0;
        *(uint4*)(hrow + 128) = w;
        *(uint4*)(hrow + 136) = make_uint4(0, 0, 0, 0);
        *(uint4*)(hrow + 144) = make_uint4(0, 0, 0, 0);
        *(uint4*)(hrow + 152) = make_uint4(0, 0, 0, 0);
    }
    for (int i = tid; i < 8 * 20; i += 256)
        *(uint4*)(Hs + (40 + i / 20) * SP + (i % 20) * 8) = make_uint4(0, 0, 0, 0);
}

// ======================= gather, 512-thread variant (layer_last) =============
template<int DEG, int SP>
__device__ __forceinline__ void g512_bf16(
    unsigned short* Hs, const unsigned short* __restrict__ x,
    const float* __restrict__ bondf,
    const int* __restrict__ an, const int* __restrict__ bn,
    int seg, int B40)
{
    const int tid = threadIdx.x;
    const int ch  = tid & 31;
    const int rg  = tid >> 5;                       // 0..15
    if (ch < 25) {
        int ai[3][DEG];
        #pragma unroll
        for (int p = 0; p < 3; ++p) {
            const int r = rg + 16 * p;
            if (r < 40) {
                const int ri = B40 + r;
                #pragma unroll
                for (int d = 0; d < DEG; ++d) ai[p][d] = an[(size_t)ri * DEG + d];
            }
        }
        uint2 sv[3], nv[3][DEG];
        #pragma unroll
        for (int p = 0; p < 3; ++p) {
            const int r = rg + 16 * p;
            if (r < 40) {
                sv[p] = *(const uint2*)(x + (size_t)(seg + B40 + r) * XS + ch * 4);
                #pragma unroll
                for (int d = 0; d < DEG; ++d)
                    nv[p][d] = *(const uint2*)(x + (size_t)ai[p][d] * XS + ch * 4);
            }
        }
        #pragma unroll
        for (int p = 0; p < 3; ++p) {
            const int r = rg + 16 * p;
            if (r < 40) {
                unsigned short* hrow = Hs + r * SP;
                *(uint2*)(hrow + ch * 4) = sv[p];
                float s0 = 0.f, s1 = 0.f, s2 = 0.f, s3 = 0.f;
                #pragma unroll
                for (int d = 0; d < DEG; ++d) {
                    s0 += bf2f(nv[p][d].x & 0xFFFFu); s1 += bf2f(nv[p][d].x >> 16);
                    s2 += bf2f(nv[p][d].y & 0xFFFFu); s3 += bf2f(nv[p][d].y >> 16);
                }
                uint2 o; o.x = pack2(s0, s1); o.y = pack2(s2, s3);
                *(uint2*)(hrow + 104 + ch * 4) = o;
            }
        }
    } else {                                        // bond rows on ch 25..31
        const int idx = rg * 7 + (ch - 25);
        if (idx < 40) {
            const int ri = B40 + idx;
            int bi[DEG];
            #pragma unroll
            for (int d = 0; d < DEG; ++d) bi[d] = bn[(size_t)ri * DEG + d];
            float2 v0[DEG], v1[DEG], v2[DEG];
            #pragma unroll
            for (int d = 0; d < DEG; ++d) {
                const float* bp = bondf + (size_t)bi[d] * 6;
                v0[d] = *(const float2*)bp;
                v1[d] = *(const float2*)(bp + 2);
                v2[d] = *(const float2*)(bp + 4);
            }
            float s0 = 0.f, s1 = 0.f, s2 = 0.f, s3 = 0.f, s4 = 0.f, s5 = 0.f;
            #pragma unroll
            for (int d = 0; d < DEG; ++d) {
                s0 += v0[d].x; s1 += v0[d].y; s2 += v1[d].x;
                s3 += v1[d].y; s4 += v2[d].x; s5 += v2[d].y;
            }
            unsigned short* hrow = Hs + idx * SP;
            uint4 w; w.x = pack2(s0, s1); w.y = pack2(s2, s3); w.z = pack2(s4, s5); w.w = 0;
            *(uint4*)(hrow + 208) = w;
            *(uint4*)(hrow + 216) = make_uint4(0, 0, 0, 0);
        }
    }
    for (int i = tid; i < 80; i += 512) {
        unsigned short* p = Hs + (i >> 1) * SP + ((i & 1) ? 204 : 100);
        *(uint2*)p = make_uint2(0, 0);
    }
    for (int i = tid; i < 8 * 28; i += 512)
        *(uint4*)(Hs + (40 + i / 28) * SP + (i % 28) * 8) = make_uint4(0, 0, 0, 0);
}

// ======================= layers 0/1: 2-chunk fused kernel (R9, proven) =======
// MODE 1: 100-elem bf16 rows (layer 1). MODE 2: 64-elem bf16 rows (layer 0).
template<int F_IN, int SELF_PAD, int MODE>
__global__ __launch_bounds__(512, 4) void layer01(
    const void* __restrict__ xin,
    const float* __restrict__ bondf,
    const int* __restrict__ an1, const int* __restrict__ bn1,
    const int* __restrict__ an2, const int* __restrict__ bn2,
    const int* __restrict__ an3, const int* __restrict__ bn3,
    const int* __restrict__ an4, const int* __restrict__ bn4,
    const unsigned short* __restrict__ Wt,  // [4][112][KP] bf16
    const float* __restrict__ bcomb,        // [4][112] fp32
    unsigned short* __restrict__ xout)      // [500000, XS] bf16
{
    constexpr int F_OUT = 100;
    constexpr int F_OUT_PAD = 112;
    constexpr int KP = (2 * SELF_PAD + 6 + 31) & ~31;   // 160 / 224
    constexpr int SP = KP + 8;

    __shared__ __align__(16) unsigned short Hs[96 * SP]; // chunk c rows at c*48
    __shared__ float ssqs[7][96];
    __shared__ __align__(16) float rn96[96];

    const int b = blockIdx.x;
    int deg, seg, pair; bool has1;
    pairseg(b, deg, seg, pair, has1);

    const int half = threadIdx.x >> 8;      // 0 or 1 -> which chunk to gather
    const int t    = threadIdx.x & 255;
    const int B40  = pair * 80 + half * 40;
    unsigned short* HsC = Hs + half * 48 * SP;

    if (half == 1 && !has1) {
        for (int i = t; i < 48 * SP / 8; i += 256)
            ((uint4*)HsC)[i] = make_uint4(0, 0, 0, 0);
    } else {
        const unsigned short* x = (const unsigned short*)xin;
        if constexpr (MODE == 1) {
            switch (deg) {
                case 1: g256_bf16<1, SP>(HsC, x, bondf, an1, bn1, seg, B40, t); break;
                case 2: g256_bf16<2, SP>(HsC, x, bondf, an2, bn2, seg, B40, t); break;
                case 3: g256_bf16<3, SP>(HsC, x, bondf, an3, bn3, seg, B40, t); break;
                default: g256_bf16<4, SP>(HsC, x, bondf, an4, bn4, seg, B40, t); break;
            }
        } else {
            switch (deg) {
                case 1: g256_bf16_64<1, SP>(HsC, x, bondf, an1, bn1, seg, B40, t); break;
                case 2: g256_bf16_64<2, SP>(HsC, x, bondf, an2, bn2, seg, B40, t); break;
                case 3: g256_bf16_64<3, SP>(HsC, x, bondf, an3, bn3, seg, B40, t); break;
                default: g256_bf16_64<4, SP>(HsC, x, bondf, an4, bn4, seg, B40, t); break;
            }
        }
    }
    __syncthreads();

    // ---- MFMA GEMM: 6 M-tiles (96 rows) x 7 N-tiles; wave wv owns N-tile wv.
    const int lane = threadIdx.x & 63;
    const int wv   = threadIdx.x >> 6;      // 0..7; wave 7 idle in GEMM
    const int n16  = lane & 15;
    const int quad = lane >> 4;

    float4v acc[6];
    #pragma unroll
    for (int mt = 0; mt < 6; ++mt) acc[mt] = (float4v){0.f, 0.f, 0.f, 0.f};

    if (wv < 7) {
        const unsigned short* Wr =
            Wt + ((size_t)(deg - 1) * F_OUT_PAD + wv * 16 + n16) * KP;
        #pragma unroll
        for (int kk = 0; kk < KP; kk += 32) {
            short8 bb = *(const short8*)(Wr + kk + quad * 8);
            short8 a[6];
            #pragma unroll
            for (int mt = 0; mt < 6; ++mt)
                a[mt] = *(const short8*)&Hs[(mt * 16 + n16) * SP + kk + quad * 8];
            #pragma unroll
            for (int mt = 0; mt < 6; ++mt)
                acc[mt] = __builtin_amdgcn_mfma_f32_16x16x32_bf16(a[mt], bb, acc[mt], 0, 0, 0);
        }
    }

    // ---- epilogue. C/D layout: col = wv*16 + n16, row = mt*16 + quad*4 + r
    float ssq[6][4];
    #pragma unroll
    for (int mt = 0; mt < 6; ++mt)
        #pragma unroll
        for (int r = 0; r < 4; ++r) ssq[mt][r] = 0.f;

    if (wv < 7) {
        const float bj = bcomb[(deg - 1) * F_OUT_PAD + wv * 16 + n16];
        #pragma unroll
        for (int mt = 0; mt < 6; ++mt)
            #pragma unroll
            for (int r = 0; r < 4; ++r) {
                float v = acc[mt][r] + bj;
                acc[mt][r] = v;
                ssq[mt][r] += v * v;
            }
        #pragma unroll
        for (int off = 1; off <= 8; off <<= 1)
            #pragma unroll
            for (int mt = 0; mt < 6; ++mt)
                #pragma unroll
                for (int r = 0; r < 4; ++r)
                    ssq[mt][r] += __shfl_xor(ssq[mt][r], off);
        if (n16 == 0)
            #pragma unroll
            for (int mt = 0; mt < 6; ++mt)
                #pragma unroll
                for (int r = 0; r < 4; ++r)
                    ssqs[wv][mt * 16 + quad * 4 + r] = ssq[mt][r];
    }
    __syncthreads();

    if (threadIdx.x < 96) {
        float s = 0.f;
        #pragma unroll
        for (int w = 0; w < 7; ++w) s += ssqs[w][threadIdx.x];
        rn96[threadIdx.x] = 1.0f / fmaxf(sqrtf(s), 1e-12f);
    }
    __syncthreads();

    const int col = wv * 16 + n16;
    if (wv < 7 && col < F_OUT) {
        #pragma unroll
        for (int mt = 0; mt < 6; ++mt) {
            const int chunk = mt / 3;
            if (chunk == 0 || has1) {
                float4 rv = *(const float4*)&rn96[mt * 16 + quad * 4];
                const float rn_[4] = {rv.x, rv.y, rv.z, rv.w};
                const int rowc0 = (mt % 3) * 16 + quad * 4;
                const int gbase = seg + pair * 80 + chunk * 40 + rowc0;
                #pragma unroll
                for (int r = 0; r < 4; ++r) {
                    if (rowc0 + r < 40) {
                        const float v = fmaxf(acc[mt][r] * rn_[r], 0.f);
                        xout[(size_t)(gbase + r) * XS + col] = f2bf(v);
                    }
                }
            }
        }
    }
}

// ======================= layer 2: fused final layer (R8, proven) =============
__global__ __launch_bounds__(512, 4) void layer_last(
    const unsigned short* __restrict__ x,
    const float* __restrict__ bondf,
    const int* __restrict__ an1, const int* __restrict__ bn1,
    const int* __restrict__ an2, const int* __restrict__ bn2,
    const int* __restrict__ an3, const int* __restrict__ bn3,
    const int* __restrict__ an4, const int* __restrict__ bn4,
    const unsigned short* __restrict__ Wt,  // [4][512][224] bf16
    const float* __restrict__ bcomb,        // [4][512] fp32
    float* __restrict__ molout)             // [25000, 512] fp32
{
    constexpr int KP = 224, SP = 232, NW = 8, JMAX = 4;

    __shared__ __align__(16) unsigned short Hs[48 * SP];
    __shared__ float ssqs[NW][48];
    __shared__ __align__(16) float rn48[48];

    const int R0 = blockIdx.x * 40;
    int deg, seg; rowseg(R0, deg, seg);
    const int B40 = R0 - seg;

    switch (deg) {
        case 1: g512_bf16<1, SP>(Hs, x, bondf, an1, bn1, seg, B40); break;
        case 2: g512_bf16<2, SP>(Hs, x, bondf, an2, bn2, seg, B40); break;
        case 3: g512_bf16<3, SP>(Hs, x, bondf, an3, bn3, seg, B40); break;
        default: g512_bf16<4, SP>(Hs, x, bondf, an4, bn4, seg, B40); break;
    }
    __syncthreads();

    const int lane = threadIdx.x & 63;
    const int wv   = threadIdx.x >> 6;
    const int n16  = lane & 15;
    const int quad = lane >> 4;

    float4v acc[JMAX][3];
    #pragma unroll
    for (int j = 0; j < JMAX; ++j)
        #pragma unroll
        for (int mt = 0; mt < 3; ++mt)
            acc[j][mt] = (float4v){0.f, 0.f, 0.f, 0.f};

    const unsigned short* Wb = Wt + (size_t)(deg - 1) * 512 * KP;

    #pragma unroll
    for (int kk = 0; kk < KP; kk += 32) {
        short8 a[3];
        #pragma unroll
        for (int mt = 0; mt < 3; ++mt)
            a[mt] = *(const short8*)&Hs[(mt * 16 + n16) * SP + kk + quad * 8];
        short8 bfr[JMAX];
        #pragma unroll
        for (int j = 0; j < JMAX; ++j) {
            const int nt = wv + NW * j;
            bfr[j] = *(const short8*)(Wb + (size_t)(nt * 16 + n16) * KP + kk + quad * 8);
        }
        #pragma unroll
        for (int j = 0; j < JMAX; ++j)
            #pragma unroll
            for (int mt = 0; mt < 3; ++mt)
                acc[j][mt] = __builtin_amdgcn_mfma_f32_16x16x32_bf16(
                    a[mt], bfr[j], acc[j][mt], 0, 0, 0);
    }

    // ---- epilogue. col = nt*16 + n16, row = mt*16 + quad*4 + r
    float ssq[3][4];
    #pragma unroll
    for (int mt = 0; mt < 3; ++mt)
        #pragma unroll
        for (int r = 0; r < 4; ++r) ssq[mt][r] = 0.f;

    #pragma unroll
    for (int j = 0; j < JMAX; ++j) {
        const int nt = wv + NW * j;
        const float bj = bcomb[(deg - 1) * 512 + nt * 16 + n16];
        #pragma unroll
        for (int mt = 0; mt < 3; ++mt)
            #pragma unroll
            for (int r = 0; r < 4; ++r) {
                float v = acc[j][mt][r] + bj;
                acc[j][mt][r] = v;
                ssq[mt][r] += v * v;
            }
    }
    #pragma unroll
    for (int off = 1; off <= 8; off <<= 1)
        #pragma unroll
        for (int mt = 0; mt < 3; ++mt)
            #pragma unroll
            for (int r = 0; r < 4; ++r)
                ssq[mt][r] += __shfl_xor(ssq[mt][r], off);
    if (n16 == 0)
        #pragma unroll
        for (int mt = 0; mt < 3; ++mt)
            #pragma unroll
            for (int r = 0; r < 4; ++r)
                ssqs[wv][mt * 16 + quad * 4 + r] = ssq[mt][r];
    __syncthreads();

    if (threadIdx.x < 48) {
        float s = 0.f;
        #pragma unroll
        for (int w = 0; w < NW; ++w) s += ssqs[w][threadIdx.x];
        rn48[threadIdx.x] = 1.0f / fmaxf(sqrtf(s), 1e-12f);
    }
    __syncthreads();

    float rn[3][4];
    #pragma unroll
    for (int mt = 0; mt < 3; ++mt) {
        float4 v = *(const float4*)&rn48[mt * 16 + quad * 4];
        rn[mt][0] = v.x; rn[mt][1] = v.y; rn[mt][2] = v.z; rn[mt][3] = v.w;
    }

    // fused molecule segment-sum: rows 0..19 -> mol 2*bid, 20..39 -> 2*bid+1
    #pragma unroll
    for (int j = 0; j < JMAX; ++j) {
        float m0 = 0.f, m1 = 0.f;
        #pragma unroll
        for (int mt = 0; mt < 3; ++mt)
            #pragma unroll
            for (int r = 0; r < 4; ++r) {
                const int row = mt * 16 + quad * 4 + r;
                if (row < 40) {
                    const float v = fmaxf(acc[j][mt][r] * rn[mt][r], 0.f);
                    if (row < 20) m0 += v; else m1 += v;
                }
            }
        m0 += __shfl_xor(m0, 16); m0 += __shfl_xor(m0, 32);
        m1 += __shfl_xor(m1, 16); m1 += __shfl_xor(m1, 32);
        if (quad == 0) {
            const int col = (wv + NW * j) * 16 + n16;
            molout[(size_t)(2 * blockIdx.x)     * 512 + col] = m0;
            molout[(size_t)(2 * blockIdx.x + 1) * 512 + col] = m1;
        }
    }
}

extern "C" void kernel_launch(void* const* d_in, const int* in_sizes, int n_in,
                              void* d_out, int out_size, void* d_ws, size_t ws_size,
                              hipStream_t stream) {
    const bool sig_order = (in_sizes[3] != 100000);

    const float* atomf = (const float*)d_in[0];   // [500000,62]
    const float* bondf = (const float*)d_in[1];   // [600000,6]
    const int *an1, *bn1, *an2, *bn2, *an3, *bn3, *an4, *bn4;
    const float *Ws0, *bs0, *Wd0, *bd0;
    const float *Ws1, *bs1, *Wd1, *bd1;
    const float *Ws2, *bs2, *Wd2, *bd2;

    if (!sig_order) {
        an1 = (const int*)d_in[2];  bn1 = (const int*)d_in[3];
        an2 = (const int*)d_in[4];  bn2 = (const int*)d_in[5];
        an3 = (const int*)d_in[6];  bn3 = (const int*)d_in[7];
        an4 = (const int*)d_in[8];  bn4 = (const int*)d_in[9];
        Ws0 = (const float*)d_in[11]; bs0 = (const float*)d_in[12];
        Wd0 = (const float*)d_in[13]; bd0 = (const float*)d_in[14];
        Ws1 = (const float*)d_in[15]; bs1 = (const float*)d_in[16];
        Wd1 = (const float*)d_in[17]; bd1 = (const float*)d_in[18];
        Ws2 = (const float*)d_in[19]; bs2 = (const float*)d_in[20];
        Wd2 = (const float*)d_in[21]; bd2 = (const float*)d_in[22];
    } else {
        an1 = (const int*)d_in[2];  an2 = (const int*)d_in[3];
        an3 = (const int*)d_in[4];  an4 = (const int*)d_in[5];
        bn1 = (const int*)d_in[6];  bn2 = (const int*)d_in[7];
        bn3 = (const int*)d_in[8];  bn4 = (const int*)d_in[9];
        Ws0 = (const float*)d_in[11]; bs0 = (const float*)d_in[12];
        Ws1 = (const float*)d_in[13]; bs1 = (const float*)d_in[14];
        Ws2 = (const float*)d_in[15]; bs2 = (const float*)d_in[16];
        Wd0 = (const float*)d_in[17]; bd0 = (const float*)d_in[18];
        Wd1 = (const float*)d_in[19]; bd1 = (const float*)d_in[20];
        Wd2 = (const float*)d_in[21]; bd2 = (const float*)d_in[22];
    }

    // workspace layout (201,273,344 B — proven footprint)
    char* w = (char*)d_ws;
    unsigned short* x1  = (unsigned short*)w;                        // 100,000,000 B
    unsigned short* x2  = (unsigned short*)(w + 100000000);          // 100,000,000 B
    unsigned short* x0b = x2;   // [500000,64] bf16 = 64 MB; dead before layer1
    unsigned short* Wt0 = (unsigned short*)(w + 200000000);          // 143,360
    float*          bc0 = (float*)(w + 200143360);                   // 1,792
    unsigned short* Wt1 = (unsigned short*)(w + 200145152);          // 200,704
    float*          bc1 = (float*)(w + 200345856);                   // 1,792
    unsigned short* Wt2 = (unsigned short*)(w + 200347648);          // 917,504
    float*          bc2 = (float*)(w + 201265152);                   // 8,192

    prep_weights<<<(4 * 112 * 160 + 255) / 256, 256, 0, stream>>>(
        Ws0, bs0, Wd0, bd0, 62, 100, 112, 160, 64, Wt0, bc0);
    prep_weights<<<(4 * 112 * 224 + 255) / 256, 256, 0, stream>>>(
        Ws1, bs1, Wd1, bd1, 100, 100, 112, 224, 104, Wt1, bc1);
    prep_weights<<<(4 * 512 * 224 + 255) / 256, 256, 0, stream>>>(
        Ws2, bs2, Wd2, bd2, 100, 512, 512, 224, 104, Wt2, bc2);
    prep_atom64<<<(500000 * 32 + 255) / 256, 256, 0, stream>>>(
        atomf, (unsigned*)x0b);

    // 2-chunk blocks: 1250 (deg1) + 2188 (deg2, 1 tail) + 1875 (deg3)
    //                 + 938 (deg4, 1 tail) = 6251
    layer01<62, 64, 2><<<6251, 512, 0, stream>>>(
        x0b, bondf, an1, bn1, an2, bn2, an3, bn3, an4, bn4, Wt0, bc0, x1);
    layer01<100, 104, 1><<<6251, 512, 0, stream>>>(
        x1, bondf, an1, bn1, an2, bn2, an3, bn3, an4, bn4, Wt1, bc1, x2);
    layer_last<<<12500, 512, 0, stream>>>(
        x2, bondf, an1, bn1, an2, bn2, an3, bn3, an4, bn4,
        Wt2, bc2, (float*)d_out);
}

// Round 7
// 767.450 us; speedup vs baseline: 2.0035x; 1.0013x over previous
//
#include <hip/hip_runtime.h>

// NeuralConvNetwork (Duvenaud fingerprint GNN), MI355X.
// Round 15: restore proven R12 config (768.5 us, passed) after the DMA
// experiment (R13/R14) killed the container twice -> convicted, abandoned.
//   Ceiling model (corrected FETCH semantics: L2-miss path, L3-served):
//   random-128B-line throughput pins at ~1.15-1.19 TB/s across ALL healthy
//   structures (R8 40-row, R9/R10 80-row, R12 byte-halved). Floors:
//   layer_last 318MB -> 267us (meas 317), layer1 ~265, layer0 ~186 (1
//   line/row via 64-col bf16), prep ~40 -> total ~756us vs 768.5 measured.
//   ~98% of the structure-invariant memory-path ceiling = practical roofline
//   for this environment (the one untested lever, global_load_lds DMA
//   gather, is unrunnable here).

#define XS 100   // bf16 elems per intermediate activation row (exact)

typedef __attribute__((ext_vector_type(8))) short short8;
typedef __attribute__((ext_vector_type(4))) float float4v;

__device__ __forceinline__ float bf2f(unsigned u) { return __uint_as_float(u << 16); }
__device__ __forceinline__ unsigned short f2bf(float f) {
    unsigned b = __float_as_uint(f);
    return (unsigned short)((b + 0x7FFFu + ((b >> 16) & 1u)) >> 16);  // RNE
}
__device__ __forceinline__ unsigned pack2(float a, float b) {
    return (unsigned)f2bf(a) | ((unsigned)f2bf(b) << 16);
}
__device__ __forceinline__ void rowseg(int r, int& deg, int& seg) {
    if (r < 100000)      { deg = 1; seg = 0;      }
    else if (r < 275000) { deg = 2; seg = 100000; }
    else if (r < 425000) { deg = 3; seg = 275000; }
    else                 { deg = 4; seg = 425000; }
}

// block id -> (deg, seg, pair, has1) for the 2-chunk grids (6251 blocks).
__device__ __forceinline__ void pairseg(int b, int& deg, int& seg, int& pair, bool& has1) {
    if (b < 1250)      { deg = 1; seg = 0;      pair = b;        has1 = true; }
    else if (b < 3438) { deg = 2; seg = 100000; pair = b - 1250; has1 = (pair != 2187); }
    else if (b < 5313) { deg = 3; seg = 275000; pair = b - 3438; has1 = true; }
    else               { deg = 4; seg = 425000; pair = b - 5313; has1 = (pair != 937); }
}

// ---- weight prep: Wt[dg][n][k]; k<F_IN -> Ws[k][n], SELF_PAD<=k<SELF_PAD+F_IN
//      -> Wd[dg][k-SELF_PAD][n], 2*SELF_PAD<=k<2*SELF_PAD+6 -> Wd bond rows.
__global__ void prep_weights(const float* __restrict__ Ws, const float* __restrict__ bs,
                             const float* __restrict__ Wd, const float* __restrict__ bd,
                             int F_IN, int F_OUT, int F_OUT_PAD, int KP, int SELF_PAD,
                             unsigned short* __restrict__ Wt, float* __restrict__ bc)
{
    int id = blockIdx.x * 256 + threadIdx.x;
    int total = 4 * F_OUT_PAD * KP;
    if (id >= total) return;
    int k  = id % KP;
    int nq = (id / KP) % F_OUT_PAD;
    int dg = id / (KP * F_OUT_PAD);
    float v = 0.f;
    if (nq < F_OUT) {
        if (k < F_IN)                                   v = Ws[(size_t)k * F_OUT + nq];
        else if (k >= SELF_PAD && k < SELF_PAD + F_IN)  v = Wd[((size_t)dg * (F_IN + 6) + (k - SELF_PAD)) * F_OUT + nq];
        else if (k >= 2 * SELF_PAD && k < 2 * SELF_PAD + 6)
            v = Wd[((size_t)dg * (F_IN + 6) + F_IN + (k - 2 * SELF_PAD)) * F_OUT + nq];
    }
    Wt[id] = f2bf(v);
    if (k == 0)
        bc[dg * F_OUT_PAD + nq] = (nq < F_OUT) ? (bs[nq] + bd[(size_t)dg * F_OUT + nq]) : 0.f;
}

// ---- atomf fp32 [500000,62] -> bf16 [500000,64] (2 zero pad cols) ----------
__global__ void prep_atom64(const float* __restrict__ af, unsigned* __restrict__ xo)
{
    int id = blockIdx.x * 256 + threadIdx.x;
    if (id >= 500000 * 32) return;
    const int row = id >> 5, c = id & 31, col = 2 * c;
    float a = (col < 62)     ? af[(size_t)row * 62 + col]     : 0.f;
    float b = (col + 1 < 62) ? af[(size_t)row * 62 + col + 1] : 0.f;
    xo[(size_t)row * 32 + c] = pack2(a, b);
}

// ======================= gathers, 256-thread variants ========================
// 100-elem bf16 rows. Hs: self[0,100) nsum[104,204) bond[208,214).
template<int DEG, int SP>
__device__ __forceinline__ void g256_bf16(
    unsigned short* Hs, const unsigned short* __restrict__ x,
    const float* __restrict__ bondf,
    const int* __restrict__ an, const int* __restrict__ bn,
    int seg, int B40, int tid)
{
    const int ch  = tid & 31;
    const int rr  = tid >> 5;                       // 0..7
    if (ch < 25) {
        int ai[5][DEG];
        #pragma unroll
        for (int p = 0; p < 5; ++p) {
            const int ri = B40 + rr + 8 * p;
            #pragma unroll
            for (int d = 0; d < DEG; ++d) ai[p][d] = an[(size_t)ri * DEG + d];
        }
        uint2 sv[5], nv[5][DEG];
        #pragma unroll
        for (int p = 0; p < 5; ++p) {
            const int atom = seg + B40 + rr + 8 * p;
            sv[p] = *(const uint2*)(x + (size_t)atom * XS + ch * 4);
            #pragma unroll
            for (int d = 0; d < DEG; ++d)
                nv[p][d] = *(const uint2*)(x + (size_t)ai[p][d] * XS + ch * 4);
        }
        #pragma unroll
        for (int p = 0; p < 5; ++p) {
            unsigned short* hrow = Hs + (rr + 8 * p) * SP;
            *(uint2*)(hrow + ch * 4) = sv[p];       // self: bit copy
            float s0 = 0.f, s1 = 0.f, s2 = 0.f, s3 = 0.f;
            #pragma unroll
            for (int d = 0; d < DEG; ++d) {
                s0 += bf2f(nv[p][d].x & 0xFFFFu); s1 += bf2f(nv[p][d].x >> 16);
                s2 += bf2f(nv[p][d].y & 0xFFFFu); s3 += bf2f(nv[p][d].y >> 16);
            }
            uint2 o; o.x = pack2(s0, s1); o.y = pack2(s2, s3);
            *(uint2*)(hrow + 104 + ch * 4) = o;
        }
    }
    if (tid < 40) {                                 // bond: one row per thread
        const int ri = B40 + tid;
        int bi[DEG];
        #pragma unroll
        for (int d = 0; d < DEG; ++d) bi[d] = bn[(size_t)ri * DEG + d];
        float2 v0[DEG], v1[DEG], v2[DEG];
        #pragma unroll
        for (int d = 0; d < DEG; ++d) {
            const float* bp = bondf + (size_t)bi[d] * 6;
            v0[d] = *(const float2*)bp;
            v1[d] = *(const float2*)(bp + 2);
            v2[d] = *(const float2*)(bp + 4);
        }
        float s0 = 0.f, s1 = 0.f, s2 = 0.f, s3 = 0.f, s4 = 0.f, s5 = 0.f;
        #pragma unroll
        for (int d = 0; d < DEG; ++d) {
            s0 += v0[d].x; s1 += v0[d].y; s2 += v1[d].x;
            s3 += v1[d].y; s4 += v2[d].x; s5 += v2[d].y;
        }
        unsigned short* hrow = Hs + tid * SP;
        uint4 w; w.x = pack2(s0, s1); w.y = pack2(s2, s3); w.z = pack2(s4, s5); w.w = 0;
        *(uint4*)(hrow + 208) = w;
        *(uint4*)(hrow + 216) = make_uint4(0, 0, 0, 0);
    }
    for (int i = tid; i < 80; i += 256) {
        unsigned short* p = Hs + (i >> 1) * SP + ((i & 1) ? 204 : 100);
        *(uint2*)p = make_uint2(0, 0);
    }
    for (int i = tid; i < 8 * 28; i += 256)
        *(uint4*)(Hs + (40 + i / 28) * SP + (i % 28) * 8) = make_uint4(0, 0, 0, 0);
}

// 64-elem bf16 rows (layer 0, padded atomf). KP=160 layout:
// self[0,64) nsum[64,128) bond[128,134); zeros to 160.
template<int DEG, int SP>
__device__ __forceinline__ void g256_bf16_64(
    unsigned short* Hs, const unsigned short* __restrict__ x,
    const float* __restrict__ bondf,
    const int* __restrict__ an, const int* __restrict__ bn,
    int seg, int B40, int tid)
{
    const int ch  = tid & 31;
    const int rr  = tid >> 5;                       // 0..7
    if (ch < 16) {
        int ai[5][DEG];
        #pragma unroll
        for (int p = 0; p < 5; ++p) {
            const int ri = B40 + rr + 8 * p;
            #pragma unroll
            for (int d = 0; d < DEG; ++d) ai[p][d] = an[(size_t)ri * DEG + d];
        }
        uint2 sv[5], nv[5][DEG];
        #pragma unroll
        for (int p = 0; p < 5; ++p) {
            const int atom = seg + B40 + rr + 8 * p;
            sv[p] = *(const uint2*)(x + (size_t)atom * 64 + ch * 4);
            #pragma unroll
            for (int d = 0; d < DEG; ++d)
                nv[p][d] = *(const uint2*)(x + (size_t)ai[p][d] * 64 + ch * 4);
        }
        #pragma unroll
        for (int p = 0; p < 5; ++p) {
            unsigned short* hrow = Hs + (rr + 8 * p) * SP;
            *(uint2*)(hrow + ch * 4) = sv[p];       // self: bit copy
            float s0 = 0.f, s1 = 0.f, s2 = 0.f, s3 = 0.f;
            #pragma unroll
            for (int d = 0; d < DEG; ++d) {
                s0 += bf2f(nv[p][d].x & 0xFFFFu); s1 += bf2f(nv[p][d].x >> 16);
                s2 += bf2f(nv[p][d].y & 0xFFFFu); s3 += bf2f(nv[p][d].y >> 16);
            }
            uint2 o; o.x = pack2(s0, s1); o.y = pack2(s2, s3);
            *(uint2*)(hrow + 64 + ch * 4) = o;
        }
    }
    if (tid < 40) {                                 // bond: one row per thread
        const int ri = B40 + tid;
        int bi[DEG];
        #pragma unroll
        for (int d = 0; d < DEG; ++d) bi[d] = bn[(size_t)ri * DEG + d];
        float2 v0[DEG], v1[DEG], v2[DEG];
        #pragma unroll
        for (int d = 0; d < DEG; ++d) {
            const float* bp = bondf + (size_t)bi[d] * 6;
            v0[d] = *(const float2*)bp;
            v1[d] = *(const float2*)(bp + 2);
            v2[d] = *(const float2*)(bp + 4);
        }
        float s0 = 0.f, s1 = 0.f, s2 = 0.f, s3 = 0.f, s4 = 0.f, s5 = 0.f;
        #pragma unroll
        for (int d = 0; d < DEG; ++d) {
            s0 += v0[d].x; s1 += v0[d].y; s2 += v1[d].x;
            s3 += v1[d].y; s4 += v2[d].x; s5 += v2[d].y;
        }
        unsigned short* hrow = Hs + tid * SP;
        uint4 w; w.x = pack2(s0, s1); w.y = pack2(s2, s3); w.z = pack2(s4, s5); w.w = 0;
        *(uint4*)(hrow + 128) = w;
        *(uint4*)(hrow + 136) = make_uint4(0, 0, 0, 0);
        *(uint4*)(hrow + 144) = make_uint4(0, 0, 0, 0);
        *(uint4*)(hrow + 152) = make_uint4(0, 0, 0, 0);
    }
    for (int i = tid; i < 8 * 20; i += 256)
        *(uint4*)(Hs + (40 + i / 20) * SP + (i % 20) * 8) = make_uint4(0, 0, 0, 0);
}

// ======================= gather, 512-thread variant (layer_last) =============
template<int DEG, int SP>
__device__ __forceinline__ void g512_bf16(
    unsigned short* Hs, const unsigned short* __restrict__ x,
    const float* __restrict__ bondf,
    const int* __restrict__ an, const int* __restrict__ bn,
    int seg, int B40)
{
    const int tid = threadIdx.x;
    const int ch  = tid & 31;
    const int rg  = tid >> 5;                       // 0..15
    if (ch < 25) {
        int ai[3][DEG];
        #pragma unroll
        for (int p = 0; p < 3; ++p) {
            const int r = rg + 16 * p;
            if (r < 40) {
                const int ri = B40 + r;
                #pragma unroll
                for (int d = 0; d < DEG; ++d) ai[p][d] = an[(size_t)ri * DEG + d];
            }
        }
        uint2 sv[3], nv[3][DEG];
        #pragma unroll
        for (int p = 0; p < 3; ++p) {
            const int r = rg + 16 * p;
            if (r < 40) {
                sv[p] = *(const uint2*)(x + (size_t)(seg + B40 + r) * XS + ch * 4);
                #pragma unroll
                for (int d = 0; d < DEG; ++d)
                    nv[p][d] = *(const uint2*)(x + (size_t)ai[p][d] * XS + ch * 4);
            }
        }
        #pragma unroll
        for (int p = 0; p < 3; ++p) {
            const int r = rg + 16 * p;
            if (r < 40) {
                unsigned short* hrow = Hs + r * SP;
                *(uint2*)(hrow + ch * 4) = sv[p];
                float s0 = 0.f, s1 = 0.f, s2 = 0.f, s3 = 0.f;
                #pragma unroll
                for (int d = 0; d < DEG; ++d) {
                    s0 += bf2f(nv[p][d].x & 0xFFFFu); s1 += bf2f(nv[p][d].x >> 16);
                    s2 += bf2f(nv[p][d].y & 0xFFFFu); s3 += bf2f(nv[p][d].y >> 16);
                }
                uint2 o; o.x = pack2(s0, s1); o.y = pack2(s2, s3);
                *(uint2*)(hrow + 104 + ch * 4) = o;
            }
        }
    } else {                                        // bond rows on ch 25..31
        const int idx = rg * 7 + (ch - 25);
        if (idx < 40) {
            const int ri = B40 + idx;
            int bi[DEG];
            #pragma unroll
            for (int d = 0; d < DEG; ++d) bi[d] = bn[(size_t)ri * DEG + d];
            float2 v0[DEG], v1[DEG], v2[DEG];
            #pragma unroll
            for (int d = 0; d < DEG; ++d) {
                const float* bp = bondf + (size_t)bi[d] * 6;
                v0[d] = *(const float2*)bp;
                v1[d] = *(const float2*)(bp + 2);
                v2[d] = *(const float2*)(bp + 4);
            }
            float s0 = 0.f, s1 = 0.f, s2 = 0.f, s3 = 0.f, s4 = 0.f, s5 = 0.f;
            #pragma unroll
            for (int d = 0; d < DEG; ++d) {
                s0 += v0[d].x; s1 += v0[d].y; s2 += v1[d].x;
                s3 += v1[d].y; s4 += v2[d].x; s5 += v2[d].y;
            }
            unsigned short* hrow = Hs + idx * SP;
            uint4 w; w.x = pack2(s0, s1); w.y = pack2(s2, s3); w.z = pack2(s4, s5); w.w = 0;
            *(uint4*)(hrow + 208) = w;
            *(uint4*)(hrow + 216) = make_uint4(0, 0, 0, 0);
        }
    }
    for (int i = tid; i < 80; i += 512) {
        unsigned short* p = Hs + (i >> 1) * SP + ((i & 1) ? 204 : 100);
        *(uint2*)p = make_uint2(0, 0);
    }
    for (int i = tid; i < 8 * 28; i += 512)
        *(uint4*)(Hs + (40 + i / 28) * SP + (i % 28) * 8) = make_uint4(0, 0, 0, 0);
}

// ======================= layers 0/1: 2-chunk fused kernel (R9, proven) =======
// MODE 1: 100-elem bf16 rows (layer 1). MODE 2: 64-elem bf16 rows (layer 0).
template<int F_IN, int SELF_PAD, int MODE>
__global__ __launch_bounds__(512, 4) void layer01(
    const void* __restrict__ xin,
    const float* __restrict__ bondf,
    const int* __restrict__ an1, const int* __restrict__ bn1,
    const int* __restrict__ an2, const int* __restrict__ bn2,
    const int* __restrict__ an3, const int* __restrict__ bn3,
    const int* __restrict__ an4, const int* __restrict__ bn4,
    const unsigned short* __restrict__ Wt,  // [4][112][KP] bf16
    const float* __restrict__ bcomb,        // [4][112] fp32
    unsigned short* __restrict__ xout)      // [500000, XS] bf16
{
    constexpr int F_OUT = 100;
    constexpr int F_OUT_PAD = 112;
    constexpr int KP = (2 * SELF_PAD + 6 + 31) & ~31;   // 160 / 224
    constexpr int SP = KP + 8;

    __shared__ __align__(16) unsigned short Hs[96 * SP]; // chunk c rows at c*48
    __shared__ float ssqs[7][96];
    __shared__ __align__(16) float rn96[96];

    const int b = blockIdx.x;
    int deg, seg, pair; bool has1;
    pairseg(b, deg, seg, pair, has1);

    const int half = threadIdx.x >> 8;      // 0 or 1 -> which chunk to gather
    const int t    = threadIdx.x & 255;
    const int B40  = pair * 80 + half * 40;
    unsigned short* HsC = Hs + half * 48 * SP;

    if (half == 1 && !has1) {
        for (int i = t; i < 48 * SP / 8; i += 256)
            ((uint4*)HsC)[i] = make_uint4(0, 0, 0, 0);
    } else {
        const unsigned short* x = (const unsigned short*)xin;
        if constexpr (MODE == 1) {
            switch (deg) {
                case 1: g256_bf16<1, SP>(HsC, x, bondf, an1, bn1, seg, B40, t); break;
                case 2: g256_bf16<2, SP>(HsC, x, bondf, an2, bn2, seg, B40, t); break;
                case 3: g256_bf16<3, SP>(HsC, x, bondf, an3, bn3, seg, B40, t); break;
                default: g256_bf16<4, SP>(HsC, x, bondf, an4, bn4, seg, B40, t); break;
            }
        } else {
            switch (deg) {
                case 1: g256_bf16_64<1, SP>(HsC, x, bondf, an1, bn1, seg, B40, t); break;
                case 2: g256_bf16_64<2, SP>(HsC, x, bondf, an2, bn2, seg, B40, t); break;
                case 3: g256_bf16_64<3, SP>(HsC, x, bondf, an3, bn3, seg, B40, t); break;
                default: g256_bf16_64<4, SP>(HsC, x, bondf, an4, bn4, seg, B40, t); break;
            }
        }
    }
    __syncthreads();

    // ---- MFMA GEMM: 6 M-tiles (96 rows) x 7 N-tiles; wave wv owns N-tile wv.
    const int lane = threadIdx.x & 63;
    const int wv   = threadIdx.x >> 6;      // 0..7; wave 7 idle in GEMM
    const int n16  = lane & 15;
    const int quad = lane >> 4;

    float4v acc[6];
    #pragma unroll
    for (int mt = 0; mt < 6; ++mt) acc[mt] = (float4v){0.f, 0.f, 0.f, 0.f};

    if (wv < 7) {
        const unsigned short* Wr =
            Wt + ((size_t)(deg - 1) * F_OUT_PAD + wv * 16 + n16) * KP;
        #pragma unroll
        for (int kk = 0; kk < KP; kk += 32) {
            short8 bb = *(const short8*)(Wr + kk + quad * 8);
            short8 a[6];
            #pragma unroll
            for (int mt = 0; mt < 6; ++mt)
                a[mt] = *(const short8*)&Hs[(mt * 16 + n16) * SP + kk + quad * 8];
            #pragma unroll
            for (int mt = 0; mt < 6; ++mt)
                acc[mt] = __builtin_amdgcn_mfma_f32_16x16x32_bf16(a[mt], bb, acc[mt], 0, 0, 0);
        }
    }

    // ---- epilogue. C/D layout: col = wv*16 + n16, row = mt*16 + quad*4 + r
    float ssq[6][4];
    #pragma unroll
    for (int mt = 0; mt < 6; ++mt)
        #pragma unroll
        for (int r = 0; r < 4; ++r) ssq[mt][r] = 0.f;

    if (wv < 7) {
        const float bj = bcomb[(deg - 1) * F_OUT_PAD + wv * 16 + n16];
        #pragma unroll
        for (int mt = 0; mt < 6; ++mt)
            #pragma unroll
            for (int r = 0; r < 4; ++r) {
                float v = acc[mt][r] + bj;
                acc[mt][r] = v;
                ssq[mt][r] += v * v;
            }
        #pragma unroll
        for (int off = 1; off <= 8; off <<= 1)
            #pragma unroll
            for (int mt = 0; mt < 6; ++mt)
                #pragma unroll
                for (int r = 0; r < 4; ++r)
                    ssq[mt][r] += __shfl_xor(ssq[mt][r], off);
        if (n16 == 0)
            #pragma unroll
            for (int mt = 0; mt < 6; ++mt)
                #pragma unroll
                for (int r = 0; r < 4; ++r)
                    ssqs[wv][mt * 16 + quad * 4 + r] = ssq[mt][r];
    }
    __syncthreads();

    if (threadIdx.x < 96) {
        float s = 0.f;
        #pragma unroll
        for (int w = 0; w < 7; ++w) s += ssqs[w][threadIdx.x];
        rn96[threadIdx.x] = 1.0f / fmaxf(sqrtf(s), 1e-12f);
    }
    __syncthreads();

    const int col = wv * 16 + n16;
    if (wv < 7 && col < F_OUT) {
        #pragma unroll
        for (int mt = 0; mt < 6; ++mt) {
            const int chunk = mt / 3;
            if (chunk == 0 || has1) {
                float4 rv = *(const float4*)&rn96[mt * 16 + quad * 4];
                const float rn_[4] = {rv.x, rv.y, rv.z, rv.w};
                const int rowc0 = (mt % 3) * 16 + quad * 4;
                const int gbase = seg + pair * 80 + chunk * 40 + rowc0;
                #pragma unroll
                for (int r = 0; r < 4; ++r) {
                    if (rowc0 + r < 40) {
                        const float v = fmaxf(acc[mt][r] * rn_[r], 0.f);
                        xout[(size_t)(gbase + r) * XS + col] = f2bf(v);
                    }
                }
            }
        }
    }
}

// ======================= layer 2: fused final layer (R8, proven) =============
__global__ __launch_bounds__(512, 4) void layer_last(
    const unsigned short* __restrict__ x,
    const float* __restrict__ bondf,
    const int* __restrict__ an1, const int* __restrict__ bn1,
    const int* __restrict__ an2, const int* __restrict__ bn2,
    const int* __restrict__ an3, const int* __restrict__ bn3,
    const int* __restrict__ an4, const int* __restrict__ bn4,
    const unsigned short* __restrict__ Wt,  // [4][512][224] bf16
    const float* __restrict__ bcomb,        // [4][512] fp32
    float* __restrict__ molout)             // [25000, 512] fp32
{
    constexpr int KP = 224, SP = 232, NW = 8, JMAX = 4;

    __shared__ __align__(16) unsigned short Hs[48 * SP];
    __shared__ float ssqs[NW][48];
    __shared__ __align__(16) float rn48[48];

    const int R0 = blockIdx.x * 40;
    int deg, seg; rowseg(R0, deg, seg);
    const int B40 = R0 - seg;

    switch (deg) {
        case 1: g512_bf16<1, SP>(Hs, x, bondf, an1, bn1, seg, B40); break;
        case 2: g512_bf16<2, SP>(Hs, x, bondf, an2, bn2, seg, B40); break;
        case 3: g512_bf16<3, SP>(Hs, x, bondf, an3, bn3, seg, B40); break;
        default: g512_bf16<4, SP>(Hs, x, bondf, an4, bn4, seg, B40); break;
    }
    __syncthreads();

    const int lane = threadIdx.x & 63;
    const int wv   = threadIdx.x >> 6;
    const int n16  = lane & 15;
    const int quad = lane >> 4;

    float4v acc[JMAX][3];
    #pragma unroll
    for (int j = 0; j < JMAX; ++j)
        #pragma unroll
        for (int mt = 0; mt < 3; ++mt)
            acc[j][mt] = (float4v){0.f, 0.f, 0.f, 0.f};

    const unsigned short* Wb = Wt + (size_t)(deg - 1) * 512 * KP;

    #pragma unroll
    for (int kk = 0; kk < KP; kk += 32) {
        short8 a[3];
        #pragma unroll
        for (int mt = 0; mt < 3; ++mt)
            a[mt] = *(const short8*)&Hs[(mt * 16 + n16) * SP + kk + quad * 8];
        short8 bfr[JMAX];
        #pragma unroll
        for (int j = 0; j < JMAX; ++j) {
            const int nt = wv + NW * j;
            bfr[j] = *(const short8*)(Wb + (size_t)(nt * 16 + n16) * KP + kk + quad * 8);
        }
        #pragma unroll
        for (int j = 0; j < JMAX; ++j)
            #pragma unroll
            for (int mt = 0; mt < 3; ++mt)
                acc[j][mt] = __builtin_amdgcn_mfma_f32_16x16x32_bf16(
                    a[mt], bfr[j], acc[j][mt], 0, 0, 0);
    }

    // ---- epilogue. col = nt*16 + n16, row = mt*16 + quad*4 + r
    float ssq[3][4];
    #pragma unroll
    for (int mt = 0; mt < 3; ++mt)
        #pragma unroll
        for (int r = 0; r < 4; ++r) ssq[mt][r] = 0.f;

    #pragma unroll
    for (int j = 0; j < JMAX; ++j) {
        const int nt = wv + NW * j;
        const float bj = bcomb[(deg - 1) * 512 + nt * 16 + n16];
        #pragma unroll
        for (int mt = 0; mt < 3; ++mt)
            #pragma unroll
            for (int r = 0; r < 4; ++r) {
                float v = acc[j][mt][r] + bj;
                acc[j][mt][r] = v;
                ssq[mt][r] += v * v;
            }
    }
    #pragma unroll
    for (int off = 1; off <= 8; off <<= 1)
        #pragma unroll
        for (int mt = 0; mt < 3; ++mt)
            #pragma unroll
            for (int r = 0; r < 4; ++r)
                ssq[mt][r] += __shfl_xor(ssq[mt][r], off);
    if (n16 == 0)
        #pragma unroll
        for (int mt = 0; mt < 3; ++mt)
            #pragma unroll
            for (int r = 0; r < 4; ++r)
                ssqs[wv][mt * 16 + quad * 4 + r] = ssq[mt][r];
    __syncthreads();

    if (threadIdx.x < 48) {
        float s = 0.f;
        #pragma unroll
        for (int w = 0; w < NW; ++w) s += ssqs[w][threadIdx.x];
        rn48[threadIdx.x] = 1.0f / fmaxf(sqrtf(s), 1e-12f);
    }
    __syncthreads();

    float rn[3][4];
    #pragma unroll
    for (int mt = 0; mt < 3; ++mt) {
        float4 v = *(const float4*)&rn48[mt * 16 + quad * 4];
        rn[mt][0] = v.x; rn[mt][1] = v.y; rn[mt][2] = v.z; rn[mt][3] = v.w;
    }

    // fused molecule segment-sum: rows 0..19 -> mol 2*bid, 20..39 -> 2*bid+1
    #pragma unroll
    for (int j = 0; j < JMAX; ++j) {
        float m0 = 0.f, m1 = 0.f;
        #pragma unroll
        for (int mt = 0; mt < 3; ++mt)
            #pragma unroll
            for (int r = 0; r < 4; ++r) {
                const int row = mt * 16 + quad * 4 + r;
                if (row < 40) {
                    const float v = fmaxf(acc[j][mt][r] * rn[mt][r], 0.f);
                    if (row < 20) m0 += v; else m1 += v;
                }
            }
        m0 += __shfl_xor(m0, 16); m0 += __shfl_xor(m0, 32);
        m1 += __shfl_xor(m1, 16); m1 += __shfl_xor(m1, 32);
        if (quad == 0) {
            const int col = (wv + NW * j) * 16 + n16;
            molout[(size_t)(2 * blockIdx.x)     * 512 + col] = m0;
            molout[(size_t)(2 * blockIdx.x + 1) * 512 + col] = m1;
        }
    }
}

extern "C" void kernel_launch(void* const* d_in, const int* in_sizes, int n_in,
                              void* d_out, int out_size, void* d_ws, size_t ws_size,
                              hipStream_t stream) {
    const bool sig_order = (in_sizes[3] != 100000);

    const float* atomf = (const float*)d_in[0];   // [500000,62]
    const float* bondf = (const float*)d_in[1];   // [600000,6]
    const int *an1, *bn1, *an2, *bn2, *an3, *bn3, *an4, *bn4;
    const float *Ws0, *bs0, *Wd0, *bd0;
    const float *Ws1, *bs1, *Wd1, *bd1;
    const float *Ws2, *bs2, *Wd2, *bd2;

    if (!sig_order) {
        an1 = (const int*)d_in[2];  bn1 = (const int*)d_in[3];
        an2 = (const int*)d_in[4];  bn2 = (const int*)d_in[5];
        an3 = (const int*)d_in[6];  bn3 = (const int*)d_in[7];
        an4 = (const int*)d_in[8];  bn4 = (const int*)d_in[9];
        Ws0 = (const float*)d_in[11]; bs0 = (const float*)d_in[12];
        Wd0 = (const float*)d_in[13]; bd0 = (const float*)d_in[14];
        Ws1 = (const float*)d_in[15]; bs1 = (const float*)d_in[16];
        Wd1 = (const float*)d_in[17]; bd1 = (const float*)d_in[18];
        Ws2 = (const float*)d_in[19]; bs2 = (const float*)d_in[20];
        Wd2 = (const float*)d_in[21]; bd2 = (const float*)d_in[22];
    } else {
        an1 = (const int*)d_in[2];  an2 = (const int*)d_in[3];
        an3 = (const int*)d_in[4];  an4 = (const int*)d_in[5];
        bn1 = (const int*)d_in[6];  bn2 = (const int*)d_in[7];
        bn3 = (const int*)d_in[8];  bn4 = (const int*)d_in[9];
        Ws0 = (const float*)d_in[11]; bs0 = (const float*)d_in[12];
        Ws1 = (const float*)d_in[13]; bs1 = (const float*)d_in[14];
        Ws2 = (const float*)d_in[15]; bs2 = (const float*)d_in[16];
        Wd0 = (const float*)d_in[17]; bd0 = (const float*)d_in[18];
        Wd1 = (const float*)d_in[19]; bd1 = (const float*)d_in[20];
        Wd2 = (const float*)d_in[21]; bd2 = (const float*)d_in[22];
    }

    // workspace layout (201,273,344 B — proven footprint)
    char* w = (char*)d_ws;
    unsigned short* x1  = (unsigned short*)w;                        // 100,000,000 B
    unsigned short* x2  = (unsigned short*)(w + 100000000);          // 100,000,000 B
    unsigned short* x0b = x2;   // [500000,64] bf16 = 64 MB; dead before layer1
    unsigned short* Wt0 = (unsigned short*)(w + 200000000);          // 143,360
    float*          bc0 = (float*)(w + 200143360);                   // 1,792
    unsigned short* Wt1 = (unsigned short*)(w + 200145152);          // 200,704
    float*          bc1 = (float*)(w + 200345856);                   // 1,792
    unsigned short* Wt2 = (unsigned short*)(w + 200347648);          // 917,504
    float*          bc2 = (float*)(w + 201265152);                   // 8,192

    prep_weights<<<(4 * 112 * 160 + 255) / 256, 256, 0, stream>>>(
        Ws0, bs0, Wd0, bd0, 62, 100, 112, 160, 64, Wt0, bc0);
    prep_weights<<<(4 * 112 * 224 + 255) / 256, 256, 0, stream>>>(
        Ws1, bs1, Wd1, bd1, 100, 100, 112, 224, 104, Wt1, bc1);
    prep_weights<<<(4 * 512 * 224 + 255) / 256, 256, 0, stream>>>(
        Ws2, bs2, Wd2, bd2, 100, 512, 512, 224, 104, Wt2, bc2);
    prep_atom64<<<(500000 * 32 + 255) / 256, 256, 0, stream>>>(
        atomf, (unsigned*)x0b);

    // 2-chunk blocks: 1250 (deg1) + 2188 (deg2, 1 tail) + 1875 (deg3)
    //                 + 938 (deg4, 1 tail) = 6251
    layer01<62, 64, 2><<<6251, 512, 0, stream>>>(
        x0b, bondf, an1, bn1, an2, bn2, an3, bn3, an4, bn4, Wt0, bc0, x1);
    layer01<100, 104, 1><<<6251, 512, 0, stream>>>(
        x1, bondf, an1, bn1, an2, bn2, an3, bn3, an4, bn4, Wt1, bc1, x2);
    layer_last<<<12500, 512, 0, stream>>>(
        x2, bondf, an1, bn1, an2, bn2, an3, bn3, an4, bn4,
        Wt2, bc2, (float*)d_out);
}